// Round 1
// baseline (125.342 us; speedup 1.0000x reference)
//
#include <hip/hip_runtime.h>
#include <hip/hip_bf16.h>

#define NB 64
#define NC 256
#define NL 2048
#define NH 8
#define KW 3
#define LP (NL - KW + 1)  // 2046

// monotonic float->uint key: order(u) == order(x)
__device__ __forceinline__ unsigned fkey(float x) {
  unsigned b = __float_as_uint(x);
  return (b & 0x80000000u) ? ~b : (b | 0x80000000u);
}

// Kernel 1: valid conv1d, all 8 heads per thread, stream src once.
__global__ __launch_bounds__(256) void conv_kernel(
    const float* __restrict__ src, const float* __restrict__ conv_w,
    const float* __restrict__ conv_b, float* __restrict__ xi) {
  const int l = blockIdx.x * 256 + threadIdx.x;
  const int b = blockIdx.y;
  if (l >= LP) return;
  float acc[NH];
#pragma unroll
  for (int h = 0; h < NH; ++h) acc[h] = 0.f;
  const float* sp = src + (size_t)b * NC * NL + l;
  for (int c = 0; c < NC; ++c) {
    float s0 = sp[0], s1 = sp[1], s2 = sp[2];
    sp += NL;
#pragma unroll
    for (int h = 0; h < NH; ++h) {
      const float* w = conv_w + (h * NC + c) * KW;  // uniform -> s_load
      acc[h] = fmaf(s0, w[0], acc[h]);
      acc[h] = fmaf(s1, w[1], acc[h]);
      acc[h] = fmaf(s2, w[2], acc[h]);
    }
  }
#pragma unroll
  for (int h = 0; h < NH; ++h)
    xi[((size_t)b * NH + h) * NL + l] = acc[h] + conv_b[h];
}

// Kernel 2: one block per (b,h). BN stats -> xn, exact radix-select of k-th
// largest (stable ties like lax.top_k), sigmoid mask, 3-tap box sum,
// write cw*M back over the xi row (deterministic, no atomics).
__global__ __launch_bounds__(256) void select_kernel(
    float* __restrict__ xi, const float* __restrict__ bn_gamma,
    const float* __restrict__ bn_beta, const float* __restrict__ comb_w,
    const int* __restrict__ kptr) {
  const int t = threadIdx.x;
  const int bh = blockIdx.x;
  const int h = bh & (NH - 1);
  __shared__ float xs[LP];
  __shared__ float smp[NL + KW - 1];  // m shifted by KW-1, zero-padded
  __shared__ int hist[256];
  __shared__ int sufs[256];
  __shared__ float rs[8];
  __shared__ int sel[2];
  __shared__ int cnt[2];

  float* row = xi + (size_t)bh * NL;
  float s1 = 0.f, s2 = 0.f;
  for (int i = t; i < LP; i += 256) {
    float v = row[i];
    xs[i] = v;
    s1 += v;
    s2 += v * v;
  }
#pragma unroll
  for (int off = 32; off > 0; off >>= 1) {
    s1 += __shfl_down(s1, off);
    s2 += __shfl_down(s2, off);
  }
  const int wid = t >> 6, lane = t & 63;
  if (lane == 0) { rs[wid] = s1; rs[wid + 4] = s2; }
  __syncthreads();
  if (t == 0) {
    float S = rs[0] + rs[1] + rs[2] + rs[3];
    float Q = rs[4] + rs[5] + rs[6] + rs[7];
    float mu = S / (float)LP;
    float var = Q / (float)LP - mu * mu;
    float inv = rsqrtf(var + 1e-5f);
    float sc = bn_gamma[h] * inv;
    rs[0] = sc;
    rs[1] = bn_beta[h] - mu * sc;
  }
  __syncthreads();
  {
    float sc = rs[0], sh = rs[1];
    for (int i = t; i < LP; i += 256) xs[i] = fmaf(xs[i], sc, sh);
  }
  // exact radix select: find bit pattern of k-th largest key
  int kk = kptr[0];
  const int ktot = kk;
  unsigned prefix = 0, pm = 0;
  for (int pass = 0; pass < 4; ++pass) {
    const int shift = 24 - 8 * pass;
    hist[t] = 0;
    __syncthreads();
    for (int i = t; i < LP; i += 256) {
      unsigned u = fkey(xs[i]);
      if ((u & pm) == prefix) atomicAdd(&hist[(u >> shift) & 255], 1);
    }
    __syncthreads();
    int v = hist[t];
    sufs[t] = v;
    __syncthreads();
#pragma unroll
    for (int off = 1; off < 256; off <<= 1) {
      int add = (t + off < 256) ? sufs[t + off] : 0;
      __syncthreads();
      sufs[t] += add;
      __syncthreads();
    }
    int higher = (t == 255) ? 0 : sufs[t + 1];
    if (sufs[t] >= kk && higher < kk) { sel[0] = t; sel[1] = kk - higher; }
    __syncthreads();
    prefix |= ((unsigned)sel[0]) << shift;
    pm |= 255u << shift;
    kk = sel[1];
    __syncthreads();
  }
  const unsigned T = prefix;
  for (int i = t; i < NL + KW - 1; i += 256) smp[i] = 0.f;
  if (t < 2) cnt[t] = 0;
  __syncthreads();
  for (int i = t; i < LP; i += 256) {
    unsigned u = fkey(xs[i]);
    if (u > T) atomicAdd(&cnt[0], 1);
    else if (u == T) atomicAdd(&cnt[1], 1);
  }
  __syncthreads();
  const int need_eq = ktot - cnt[0];
  if (cnt[1] == need_eq) {
    for (int i = t; i < LP; i += 256) {
      float x = xs[i];
      if (fkey(x) >= T) smp[i + KW - 1] = 1.f / (1.f + __expf(-x));
    }
  } else {  // rare tie case: stable lowest-index-first like lax.top_k
    for (int i = t; i < LP; i += 256) {
      float x = xs[i];
      if (fkey(x) > T) smp[i + KW - 1] = 1.f / (1.f + __expf(-x));
    }
    if (t == 0) {
      int taken = 0;
      for (int i = 0; i < LP && taken < need_eq; ++i) {
        float x = xs[i];
        if (fkey(x) == T) { smp[i + KW - 1] = 1.f / (1.f + __expf(-x)); ++taken; }
      }
    }
  }
  __syncthreads();
  const float cw = comb_w[h] * (1.0f / (float)KW);
  for (int l = t; l < NL; l += 256) {
    float Mv = smp[l + 2] + smp[l + 1] + smp[l];
    row[l] = cw * Mv;  // overwrite xi row with this head's gate contribution
  }
}

// Kernel 3: gate[b,l] = sum_h contribution[b,h,l]
__global__ __launch_bounds__(256) void gate_combine(
    const float* __restrict__ xi, float* __restrict__ gate) {
  const int idx = blockIdx.x * 256 + threadIdx.x;  // 0 .. NB*NL-1
  const int b = idx >> 11;
  const int l = idx & (NL - 1);
  const float* p = xi + ((size_t)b * NH) * NL + l;
  float s = 0.f;
#pragma unroll
  for (int h = 0; h < NH; ++h) s += p[(size_t)h * NL];
  gate[idx] = s;
}

// Kernel 4: out = src * gate[b,l] + comb_b, float4 vectorized.
__global__ __launch_bounds__(256) void scale_kernel(
    const float* __restrict__ src, const float* __restrict__ gate,
    const float* __restrict__ comb_b, float* __restrict__ out) {
  const size_t total = (size_t)NB * NC * NL / 4;
  const float cb = comb_b[0];
  for (size_t idx = (size_t)blockIdx.x * blockDim.x + threadIdx.x; idx < total;
       idx += (size_t)gridDim.x * blockDim.x) {
    const size_t e = idx * 4;
    const int l = (int)(e & (NL - 1));
    const int b = (int)(e >> 19);  // C*L = 2^19
    float4 sv = ((const float4*)src)[idx];
    float4 gv = *(const float4*)(gate + (size_t)b * NL + l);
    float4 ov;
    ov.x = fmaf(sv.x, gv.x, cb);
    ov.y = fmaf(sv.y, gv.y, cb);
    ov.z = fmaf(sv.z, gv.z, cb);
    ov.w = fmaf(sv.w, gv.w, cb);
    ((float4*)out)[idx] = ov;
  }
}

extern "C" void kernel_launch(void* const* d_in, const int* in_sizes, int n_in,
                              void* d_out, int out_size, void* d_ws, size_t ws_size,
                              hipStream_t stream) {
  const float* src = (const float*)d_in[0];
  const float* conv_w = (const float*)d_in[1];
  const float* conv_b = (const float*)d_in[2];
  const float* bn_gamma = (const float*)d_in[3];
  const float* bn_beta = (const float*)d_in[4];
  const float* comb_w = (const float*)d_in[5];
  const float* comb_b = (const float*)d_in[6];
  const int* kptr = (const int*)d_in[7];
  float* out = (float*)d_out;

  float* xi = (float*)d_ws;                       // NB*NH*NL floats (4 MB)
  float* gate = xi + (size_t)NB * NH * NL;        // NB*NL floats (512 KB)

  conv_kernel<<<dim3((LP + 255) / 256, NB), 256, 0, stream>>>(src, conv_w, conv_b, xi);
  select_kernel<<<NB * NH, 256, 0, stream>>>(xi, bn_gamma, bn_beta, comb_w, kptr);
  gate_combine<<<(NB * NL) / 256, 256, 0, stream>>>(xi, gate);
  scale_kernel<<<2048, 256, 0, stream>>>(src, gate, comb_b, out);
}

// Round 2
// 113.796 us; speedup vs baseline: 1.1015x; 1.1015x over previous
//
#include <hip/hip_runtime.h>
#include <hip/hip_bf16.h>

#define NB 64
#define NC 256
#define NL 2048
#define NH 8
#define KW 3
#define LP (NL - KW + 1)  // 2046
#define NCHUNK 4
#define CPC (NC / NCHUNK)  // 64 channels per chunk

// monotonic float->uint key: order(u) == order(x)
__device__ __forceinline__ unsigned fkey(float x) {
  unsigned b = __float_as_uint(x);
  return (b & 0x80000000u) ? ~b : (b | 0x80000000u);
}

// Kernel 1: valid conv1d partial sums. Grid (LP/256, NB, NCHUNK): each block
// reduces 64 channels for 256 l positions x 8 heads. Partials land in d_out
// (used as 16 MB scratch; fully overwritten later by scale_kernel).
// c-loop unrolled x2 -> 6 loads in flight per wave.
__global__ __launch_bounds__(256) void conv_partial(
    const float* __restrict__ src, const float* __restrict__ conv_w,
    float* __restrict__ part) {
  const int l = blockIdx.x * 256 + threadIdx.x;
  const int b = blockIdx.y;
  const int cc = blockIdx.z;
  if (l >= LP) return;
  float acc[NH];
#pragma unroll
  for (int h = 0; h < NH; ++h) acc[h] = 0.f;
  const int c0 = cc * CPC;
  const float* sp = src + ((size_t)b * NC + c0) * NL + l;
  for (int c = 0; c < CPC; c += 2) {
    float a0 = sp[0], a1 = sp[1], a2 = sp[2];
    float b0 = sp[NL], b1 = sp[NL + 1], b2 = sp[NL + 2];
    sp += 2 * NL;
#pragma unroll
    for (int h = 0; h < NH; ++h) {
      const float* w = conv_w + ((h * NC + c0 + c) * KW);  // uniform -> s_load
      acc[h] = fmaf(a0, w[0], acc[h]);
      acc[h] = fmaf(a1, w[1], acc[h]);
      acc[h] = fmaf(a2, w[2], acc[h]);
      acc[h] = fmaf(b0, w[3], acc[h]);
      acc[h] = fmaf(b1, w[4], acc[h]);
      acc[h] = fmaf(b2, w[5], acc[h]);
    }
  }
#pragma unroll
  for (int h = 0; h < NH; ++h)
    part[((size_t)cc * NB * NH + blockIdx.y * NH + h) * NL + l] = acc[h];
}

// Kernel 2: one block per (b,h). Sum the 4 conv partials (+bias), BN stats ->
// xn, exact radix-select of k-th largest (stable ties like lax.top_k),
// sigmoid mask, 3-tap box sum, write cw*M into the xi row (deterministic).
__global__ __launch_bounds__(256) void select_kernel(
    const float* __restrict__ part, float* __restrict__ xi,
    const float* __restrict__ conv_b, const float* __restrict__ bn_gamma,
    const float* __restrict__ bn_beta, const float* __restrict__ comb_w,
    const int* __restrict__ kptr) {
  const int t = threadIdx.x;
  const int bh = blockIdx.x;
  const int h = bh & (NH - 1);
  __shared__ float xs[LP];
  __shared__ float smp[NL + KW - 1];  // m shifted by KW-1, zero-padded
  __shared__ int hist[256];
  __shared__ int sufs[256];
  __shared__ float rs[8];
  __shared__ int sel[2];
  __shared__ int cnt[2];

  const float* p0 = part + ((size_t)0 * NB * NH + bh) * NL;
  const float* p1 = part + ((size_t)1 * NB * NH + bh) * NL;
  const float* p2 = part + ((size_t)2 * NB * NH + bh) * NL;
  const float* p3 = part + ((size_t)3 * NB * NH + bh) * NL;
  const float cb = conv_b[h];
  float s1 = 0.f, s2 = 0.f;
  for (int i = t; i < LP; i += 256) {
    float v = ((p0[i] + p1[i]) + (p2[i] + p3[i])) + cb;
    xs[i] = v;
    s1 += v;
    s2 += v * v;
  }
#pragma unroll
  for (int off = 32; off > 0; off >>= 1) {
    s1 += __shfl_down(s1, off);
    s2 += __shfl_down(s2, off);
  }
  const int wid = t >> 6, lane = t & 63;
  if (lane == 0) { rs[wid] = s1; rs[wid + 4] = s2; }
  __syncthreads();
  if (t == 0) {
    float S = rs[0] + rs[1] + rs[2] + rs[3];
    float Q = rs[4] + rs[5] + rs[6] + rs[7];
    float mu = S / (float)LP;
    float var = Q / (float)LP - mu * mu;
    float inv = rsqrtf(var + 1e-5f);
    float sc = bn_gamma[h] * inv;
    rs[0] = sc;
    rs[1] = bn_beta[h] - mu * sc;
  }
  __syncthreads();
  {
    float sc = rs[0], sh = rs[1];
    for (int i = t; i < LP; i += 256) xs[i] = fmaf(xs[i], sc, sh);
  }
  // exact radix select: find bit pattern of k-th largest key
  int kk = kptr[0];
  const int ktot = kk;
  unsigned prefix = 0, pm = 0;
  for (int pass = 0; pass < 4; ++pass) {
    const int shift = 24 - 8 * pass;
    hist[t] = 0;
    __syncthreads();
    for (int i = t; i < LP; i += 256) {
      unsigned u = fkey(xs[i]);
      if ((u & pm) == prefix) atomicAdd(&hist[(u >> shift) & 255], 1);
    }
    __syncthreads();
    int v = hist[t];
    sufs[t] = v;
    __syncthreads();
#pragma unroll
    for (int off = 1; off < 256; off <<= 1) {
      int add = (t + off < 256) ? sufs[t + off] : 0;
      __syncthreads();
      sufs[t] += add;
      __syncthreads();
    }
    int higher = (t == 255) ? 0 : sufs[t + 1];
    if (sufs[t] >= kk && higher < kk) { sel[0] = t; sel[1] = kk - higher; }
    __syncthreads();
    prefix |= ((unsigned)sel[0]) << shift;
    pm |= 255u << shift;
    kk = sel[1];
    __syncthreads();
  }
  const unsigned T = prefix;
  for (int i = t; i < NL + KW - 1; i += 256) smp[i] = 0.f;
  if (t < 2) cnt[t] = 0;
  __syncthreads();
  for (int i = t; i < LP; i += 256) {
    unsigned u = fkey(xs[i]);
    if (u > T) atomicAdd(&cnt[0], 1);
    else if (u == T) atomicAdd(&cnt[1], 1);
  }
  __syncthreads();
  const int need_eq = ktot - cnt[0];
  if (cnt[1] == need_eq) {
    for (int i = t; i < LP; i += 256) {
      float x = xs[i];
      if (fkey(x) >= T) smp[i + KW - 1] = 1.f / (1.f + __expf(-x));
    }
  } else {  // rare tie case: stable lowest-index-first like lax.top_k
    for (int i = t; i < LP; i += 256) {
      float x = xs[i];
      if (fkey(x) > T) smp[i + KW - 1] = 1.f / (1.f + __expf(-x));
    }
    if (t == 0) {
      int taken = 0;
      for (int i = 0; i < LP && taken < need_eq; ++i) {
        float x = xs[i];
        if (fkey(x) == T) { smp[i + KW - 1] = 1.f / (1.f + __expf(-x)); ++taken; }
      }
    }
  }
  __syncthreads();
  const float cw = comb_w[h] * (1.0f / (float)KW);
  float* row = xi + (size_t)bh * NL;
  for (int l = t; l < NL; l += 256) {
    float Mv = smp[l + 2] + smp[l + 1] + smp[l];
    row[l] = cw * Mv;  // this head's gate contribution
  }
}

// Kernel 3: gate[b,l] = sum_h contribution[b,h,l]
__global__ __launch_bounds__(256) void gate_combine(
    const float* __restrict__ xi, float* __restrict__ gate) {
  const int idx = blockIdx.x * 256 + threadIdx.x;  // 0 .. NB*NL-1
  const int b = idx >> 11;
  const int l = idx & (NL - 1);
  const float* p = xi + ((size_t)b * NH) * NL + l;
  float s = 0.f;
#pragma unroll
  for (int h = 0; h < NH; ++h) s += p[(size_t)h * NL];
  gate[idx] = s;
}

// Kernel 4: out = src * gate[b,l] + comb_b, float4 vectorized.
__global__ __launch_bounds__(256) void scale_kernel(
    const float* __restrict__ src, const float* __restrict__ gate,
    const float* __restrict__ comb_b, float* __restrict__ out) {
  const size_t total = (size_t)NB * NC * NL / 4;
  const float cb = comb_b[0];
  for (size_t idx = (size_t)blockIdx.x * blockDim.x + threadIdx.x; idx < total;
       idx += (size_t)gridDim.x * blockDim.x) {
    const size_t e = idx * 4;
    const int l = (int)(e & (NL - 1));
    const int b = (int)(e >> 19);  // C*L = 2^19
    float4 sv = ((const float4*)src)[idx];
    float4 gv = *(const float4*)(gate + (size_t)b * NL + l);
    float4 ov;
    ov.x = fmaf(sv.x, gv.x, cb);
    ov.y = fmaf(sv.y, gv.y, cb);
    ov.z = fmaf(sv.z, gv.z, cb);
    ov.w = fmaf(sv.w, gv.w, cb);
    ((float4*)out)[idx] = ov;
  }
}

extern "C" void kernel_launch(void* const* d_in, const int* in_sizes, int n_in,
                              void* d_out, int out_size, void* d_ws, size_t ws_size,
                              hipStream_t stream) {
  const float* src = (const float*)d_in[0];
  const float* conv_w = (const float*)d_in[1];
  const float* conv_b = (const float*)d_in[2];
  const float* bn_gamma = (const float*)d_in[3];
  const float* bn_beta = (const float*)d_in[4];
  const float* comb_w = (const float*)d_in[5];
  const float* comb_b = (const float*)d_in[6];
  const int* kptr = (const int*)d_in[7];
  float* out = (float*)d_out;

  float* xi = (float*)d_ws;                       // NB*NH*NL floats (4 MB)
  float* gate = xi + (size_t)NB * NH * NL;        // NB*NL floats (512 KB)
  float* part = out;                              // 16 MB scratch inside d_out
                                                  // (fully overwritten by scale_kernel)

  conv_partial<<<dim3((LP + 255) / 256, NB, NCHUNK), 256, 0, stream>>>(src, conv_w, part);
  select_kernel<<<NB * NH, 256, 0, stream>>>(part, xi, conv_b, bn_gamma, bn_beta, comb_w, kptr);
  gate_combine<<<(NB * NL) / 256, 256, 0, stream>>>(xi, gate);
  scale_kernel<<<2048, 256, 0, stream>>>(src, gate, comb_b, out);
}